// Round 14
// baseline (480.115 us; speedup 1.0000x reference)
//
#include <hip/hip_runtime.h>
#include <math.h>

#define NPTS 32768
#define HID  128
#define PPB  4      // points per block; 13 channels padded to 16 rows each -> 64 M-rows
#define NCH  13
#define KB   32     // fp32 fallback K-block

typedef __attribute__((ext_vector_type(8))) _Float16 f16x8;
typedef __attribute__((ext_vector_type(4))) float f32x4;

struct PinnArgs {
  const float* x; const float* y; const float* t;
  const float* W[9]; const float* b[9];
  const float* lam1; const float* lam2;
  float* out;
  const _Float16* wt;   // [7 layers][2 planes hi/lo][128 n][128 k]
};

struct PrepArgs { const float* W[7]; _Float16* out; };

// ---- cross-lane 16/32 swaps (VALU permlane on gfx950; shfl fallback) ----
// Network (R9/R10 HW-verified): given per-lane a0..a3 with lane-quad kg,
// {swap16(a0,a1); swap16(a2,a3); swap32(a0,a2); swap32(a1,a3)} transposes the
// 4x4 (quad kg x array idx q) matrix: lane(kg,lr).z_i = lane(i,lr).a_kg.
__device__ __forceinline__ void swap16(float& a, float& b) {
#if __has_builtin(__builtin_amdgcn_permlane16_swap)
  auto r = __builtin_amdgcn_permlane16_swap(__float_as_uint(a), __float_as_uint(b), false, false);
  a = __uint_as_float(r[0]); b = __uint_as_float(r[1]);
#else
  const bool odd = (threadIdx.x >> 4) & 1;
  const float sa = __shfl_xor(a, 16, 64), sb = __shfl_xor(b, 16, 64);
  const float na = odd ? sb : a;
  const float nb = odd ? b : sa;
  a = na; b = nb;
#endif
}
__device__ __forceinline__ void swap32(float& a, float& b) {
#if __has_builtin(__builtin_amdgcn_permlane32_swap)
  auto r = __builtin_amdgcn_permlane32_swap(__float_as_uint(a), __float_as_uint(b), false, false);
  a = __uint_as_float(r[0]); b = __uint_as_float(r[1]);
#else
  const bool up = (threadIdx.x >> 5) & 1;
  const float sa = __shfl_xor(a, 32, 64), sb = __shfl_xor(b, 32, 64);
  const float na = up ? sb : a;
  const float nb = up ? b : sa;
  a = na; b = nb;
#endif
}

// Fast tanh (R11-exonerated: absmax bit-identical to libm tanhf run).
__device__ __forceinline__ float tanh_fast(float z) {
  const float zc = fminf(fmaxf(z, -15.f), 15.f);
  const float e  = __expf(2.f * zc);
  return 1.f - 2.f * __builtin_amdgcn_rcpf(e + 1.f);
}

// 13-channel Faa di Bruno composition of a = tanh(z).
// Channels: [0]=val, [1]=gx,[2]=gy,[3]=gt,
// [4]=Hxx,[5]=Hxy,[6]=Hxt,[7]=Hyy,[8]=Hyt,
// [9]=Txxx,[10]=Txxy,[11]=Txyy,[12]=Tyyy.  Closed set (R6-verified).
__device__ __forceinline__ void compose13(const float z[NCH], float o[NCH]) {
  const float v  = tanh_fast(z[0]);
  const float f1 = 1.f - v * v;
  const float f2 = -2.f * v * f1;
  const float f3 = f1 * (4.f * v * v - 2.f * f1);
  const float gx = z[1], gy = z[2], gt = z[3];
  const float hxx = z[4], hxy = z[5], hxt = z[6], hyy = z[7], hyt = z[8];
  o[0] = v;
  o[1] = f1 * gx; o[2] = f1 * gy; o[3] = f1 * gt;
  o[4] = f2 * gx * gx + f1 * hxx;
  o[5] = f2 * gx * gy + f1 * hxy;
  o[6] = f2 * gx * gt + f1 * hxt;
  o[7] = f2 * gy * gy + f1 * hyy;
  o[8] = f2 * gy * gt + f1 * hyt;
  o[9]  = f3 * gx * gx * gx + f2 * (3.f * hxx * gx)            + f1 * z[9];
  o[10] = f3 * gx * gx * gy + f2 * (hxx * gy + 2.f * hxy * gx) + f1 * z[10];
  o[11] = f3 * gx * gy * gy + f2 * (2.f * hxy * gy + hyy * gx) + f1 * z[11];
  o[12] = f3 * gy * gy * gy + f2 * (3.f * hyy * gy)            + f1 * z[12];
}

// Weight prep: W^T hi/lo f16 planes. wt[(L*2+plane)*16384 + n*128 + k]
__global__ __launch_bounds__(256) void prep_w16(PrepArgs P) {
  const int idx = blockIdx.x * 256 + threadIdx.x;
  if (idx >= 7 * 16384) return;
  const int L = idx >> 14;
  const int r = idx & 16383;
  const int n = r & 127;
  const int k = r >> 7;
  const float w = P.W[L][k * HID + n];
  const _Float16 hi = (_Float16)w;
  const _Float16 lo = (_Float16)(w - (float)hi);
  P.out[(size_t)(L * 2 + 0) * 16384 + n * 128 + k] = hi;
  P.out[(size_t)(L * 2 + 1) * 16384 + n * 128 + k] = lo;
}

// ---- A-plane column swizzle (R10/R11-proven layout) ----
// Physical 16B-block = logical block ^ rowhi (rowhi = row>>4). Bijective
// within a row -> bit-exact.  R12/R13 post-mortem: pad-free 32KB planes
// never yielded the 5th block/CU (runtime LDS reserve) and swzb cost VALU;
// reverted to this padded 136-stride layout (530us proven).
__device__ __forceinline__ int swz(int j, int rowhi) {
  return (((j >> 3) ^ rowhi) << 3) | (j & 7);
}

// R12 lesson: never set launch_bounds below natural VGPR (48-cap spilled ->
// 1.1GB scratch). (256,4) caps at 128 VGPR; natural here ~116 with B-prefetch.
__global__ __launch_bounds__(256, 4) void pinn_mfma(PinnArgs A) {
  __shared__ _Float16 Ah[64][136];  // 17408 B hi plane; row = p*16+c
  __shared__ _Float16 Al[64][136];  // 17408 B lo plane
  const int tid  = threadIdx.x;
  const int wave = tid >> 6;
  const int lane = tid & 63;
  const int kg   = lane >> 4;   // 0..3
  const int lr   = lane & 15;   // 0..15
  const int pbase = blockIdx.x * PPB;

  // zero pad rows (c=13..15 of each point stripe); never rewritten
  if (tid < 136) {
#pragma unroll
    for (int pp = 0; pp < PPB; ++pp)
#pragma unroll
      for (int c = NCH; c < 16; ++c) {
        Ah[pp * 16 + c][tid] = (_Float16)0.f;
        Al[pp * 16 + c][tid] = (_Float16)0.f;
      }
  }

  // ---------- layer 0: 3 -> 128 ----------
  for (int t = tid; t < PPB * HID; t += 256) {
    const int p = t >> 7, j = t & 127;
    const int gp = pbase + p;
    const float xv = A.x[gp], yv = A.y[gp], tv = A.t[gp];
    const float wx = A.W[0][j], wy = A.W[0][HID + j], wz = A.W[0][2 * HID + j];
    float z[NCH], o[NCH];
    z[0] = fmaf(wx, xv, fmaf(wy, yv, fmaf(wz, tv, A.b[0][j])));
    z[1] = wx; z[2] = wy; z[3] = wz;
#pragma unroll
    for (int c = 4; c < NCH; ++c) z[c] = 0.f;
    compose13(z, o);
    const int pj = swz(j, p);
#pragma unroll
    for (int c = 0; c < NCH; ++c) {
      const _Float16 hi = (_Float16)o[c];
      Ah[p * 16 + c][pj] = hi;
      Al[p * 16 + c][pj] = (_Float16)(o[c] - (float)hi);
    }
  }
  __syncthreads();

  // B-fragment loader (up-front per layer: R7/R9 lesson — never in k-loop).
#define LOADB(DH, DL, WHP, WLP)                                               \
  {                                                                           \
    _Pragma("unroll")                                                         \
    for (int nt = 0; nt < 2; ++nt) {                                          \
      const int col = wave * 32 + nt * 16 + lr;                               \
      _Pragma("unroll")                                                       \
      for (int ks = 0; ks < 4; ++ks) {                                        \
        const int k0 = ks * 32 + kg * 8;                                      \
        DH[nt][ks] = *(const f16x8*)((WHP) + col * 128 + k0);                 \
        DL[nt][ks] = *(const f16x8*)((WLP) + col * 128 + k0);                 \
      }                                                                       \
    }                                                                         \
  }

  // ---------- layers 1..7: GEMM + permlane transpose, B double-buffered ----
  // R14: prefetch layer L+1's B right after layer L's MFMA loop (T14
  // issue-early) — L2 latency hides under compose + barriers. Loop fully
  // unrolled so the double-buffer index is compile-time (rule #20).
  f16x8 bh[2][2][4], bl[2][2][4];
  LOADB(bh[0], bl[0], A.wt, A.wt + 16384);

#pragma unroll
  for (int L = 1; L <= 7; ++L) {
    const int cur = (L - 1) & 1, nxt = L & 1;
    f32x4 acc[4][2];   // [m][nt]; m-tile == point m (16 rows/point)
#pragma unroll
    for (int m = 0; m < 4; ++m)
#pragma unroll
      for (int nt = 0; nt < 2; ++nt) acc[m][nt] = (f32x4)(0.f);

#pragma unroll
    for (int ks = 0; ks < 4; ++ks) {
#pragma unroll
      for (int m = 0; m < 4; ++m) {
        const int row = m * 16 + lr;
        // logical 16B-block 4ks+kg at rowhi==m -> phys 4ks + (kg^m)
        const int kb = (4 * ks + (kg ^ m)) * 8;
        const f16x8 ah = *(const f16x8*)&Ah[row][kb];
        const f16x8 al = *(const f16x8*)&Al[row][kb];
#pragma unroll
        for (int nt = 0; nt < 2; ++nt) {
          acc[m][nt] = __builtin_amdgcn_mfma_f32_16x16x32_f16(ah, bh[cur][nt][ks], acc[m][nt], 0, 0, 0);
          acc[m][nt] = __builtin_amdgcn_mfma_f32_16x16x32_f16(ah, bl[cur][nt][ks], acc[m][nt], 0, 0, 0);
          acc[m][nt] = __builtin_amdgcn_mfma_f32_16x16x32_f16(al, bh[cur][nt][ks], acc[m][nt], 0, 0, 0);
        }
      }
    }

    // prefetch next layer's B (independent of LDS state; consumed after the
    // two barriers below — latency fully hidden)
    if (L < 7) {
      const _Float16* WHn = A.wt + (size_t)L * 2 * 16384;
      LOADB(bh[nxt], bl[nxt], WHn, WHn + 16384);
    }

    // ---- in-register 4x4 quad transpose across m (no Z LDS round-trip) ----
    const float* __restrict__ bb = A.b[L];
    float oo[2][NCH];
#pragma unroll
    for (int nt = 0; nt < 2; ++nt) {
      float z[16];
#pragma unroll
      for (int r = 0; r < 4; ++r) {
        float a0 = acc[0][nt][r], a1 = acc[1][nt][r];
        float a2 = acc[2][nt][r], a3 = acc[3][nt][r];
        swap16(a0, a1); swap16(a2, a3);
        swap32(a0, a2); swap32(a1, a3);
        z[0 + r] = a0; z[4 + r] = a1; z[8 + r] = a2; z[12 + r] = a3;
      }
      z[0] += bb[wave * 32 + nt * 16 + lr];
      compose13(z, oo[nt]);
    }

    __syncthreads();   // all waves' A-fragment LDS reads complete
#pragma unroll
    for (int nt = 0; nt < 2; ++nt) {
      const int j  = wave * 32 + nt * 16 + lr;
      const int pj = swz(j, kg);        // rowhi == kg for rows kg*16+c
#pragma unroll
      for (int c = 0; c < NCH; ++c) {
        const _Float16 hi = (_Float16)oo[nt][c];
        Ah[kg * 16 + c][pj] = hi;
        Al[kg * 16 + c][pj] = (_Float16)(oo[nt][c] - (float)hi);
      }
    }
    __syncthreads();   // new activations visible before next layer's reads
  }
#undef LOADB

  // ---------- layer 8 (column 0) + outputs ----------
  {
    const int p = wave, gp = pbase + p;
    const float w0 = A.W[8][2 * lane];
    const float w1 = A.W[8][2 * (lane + 64)];
    const int pj0 = swz(lane, p);
    const int pj1 = swz(lane + 64, p);
    float zc[NCH];
#pragma unroll
    for (int c = 0; c < NCH; ++c) {
      const int rr = p * 16 + c;
      const float s0 = (float)Ah[rr][pj0] + (float)Al[rr][pj0];
      const float s1 = (float)Ah[rr][pj1] + (float)Al[rr][pj1];
      zc[c] = fmaf(s0, w0, s1 * w1);
    }
#pragma unroll
    for (int off = 32; off; off >>= 1) {
#pragma unroll
      for (int c = 0; c < NCH; ++c) zc[c] += __shfl_xor(zc[c], off, 64);
    }
    if (lane == 0) {
      zc[0] += A.b[8][0];
      float o[NCH];
      compose13(zc, o);
      const float u  =  o[2];            // psi_y
      const float vv = -o[1];            // -psi_x
      const float ux =  o[5],  uy =  o[7],  ut =  o[8];
      const float vx = -o[4],  vy = -o[5],  vt = -o[6];
      const float uxx =  o[10], uyy =  o[12];
      const float vxx = -o[9],  vyy = -o[11];
      const float l1 = A.lam1[0], l2 = A.lam2[0];
      const float fu = ut + l1 * (u * ux + vv * uy) - l2 * (uxx + uyy);
      const float fv = vt + l1 * (u * vx + vv * vy) - l2 * (vxx + vyy);
      A.out[gp]            = u;
      A.out[NPTS + gp]     = vv;
      A.out[2 * NPTS + gp] = fu;
      A.out[3 * NPTS + gp] = fv;
    }
  }
}

// ---------------- fp32 fallback (proven round-1 kernel, 20-channel) ----------------
__device__ __forceinline__ void compose20(const float z[20], float o[20]) {
  const float v  = tanhf(z[0]);
  const float f1 = 1.f - v * v;
  const float f2 = -2.f * v * f1;
  const float f3 = f1 * (4.f * v * v - 2.f * f1);
  const float gx = z[1], gy = z[2], gt = z[3];
  const float hxx = z[4], hxy = z[5], hxz = z[6], hyy = z[7], hyz = z[8], hzz = z[9];
  o[0] = v;
  o[1] = f1 * gx; o[2] = f1 * gy; o[3] = f1 * gt;
  o[4] = f2 * gx * gx + f1 * hxx;
  o[5] = f2 * gx * gy + f1 * hxy;
  o[6] = f2 * gx * gt + f1 * hxz;
  o[7] = f2 * gy * gy + f1 * hyy;
  o[8] = f2 * gy * gt + f1 * hyz;
  o[9] = f2 * gt * gt + f1 * hzz;
  o[10] = f3 * gx * gx * gx + f2 * (3.f * hxx * gx)                 + f1 * z[10];
  o[11] = f3 * gx * gx * gy + f2 * (hxx * gy + 2.f * hxy * gx)      + f1 * z[11];
  o[12] = f3 * gx * gx * gt + f2 * (hxx * gt + 2.f * hxz * gx)      + f1 * z[12];
  o[13] = f3 * gx * gy * gy + f2 * (2.f * hxy * gy + hyy * gx)      + f1 * z[13];
  o[14] = f3 * gx * gy * gt + f2 * (hxy * gt + hxz * gy + hyz * gx) + f1 * z[14];
  o[15] = f3 * gx * gt * gt + f2 * (2.f * hxz * gt + hzz * gx)      + f1 * z[15];
  o[16] = f3 * gy * gy * gy + f2 * (3.f * hyy * gy)                 + f1 * z[16];
  o[17] = f3 * gy * gy * gt + f2 * (hyy * gt + 2.f * hyz * gy)      + f1 * z[17];
  o[18] = f3 * gy * gt * gt + f2 * (2.f * hyz * gt + hzz * gy)      + f1 * z[18];
  o[19] = f3 * gt * gt * gt + f2 * (3.f * hzz * gt)                 + f1 * z[19];
}

__global__ __launch_bounds__(256) void pinn_fp32(PinnArgs A) {
  __shared__ float S[4][HID][20];
  __shared__ float Wt[KB][HID];
  const int wave = threadIdx.x >> 6;
  const int lane = threadIdx.x & 63;
  const int p    = blockIdx.x * 4 + wave;
  const int j0   = lane * 2;
  {
    const float xv = A.x[p], yv = A.y[p], tv = A.t[p];
    const float* W0 = A.W[0];
    const float* b0 = A.b[0];
#pragma unroll
    for (int jj = 0; jj < 2; ++jj) {
      const int j = j0 + jj;
      const float wx = W0[j], wy = W0[HID + j], wz = W0[2 * HID + j];
      float z[20];
      z[0] = fmaf(wx, xv, fmaf(wy, yv, fmaf(wz, tv, b0[j])));
      z[1] = wx; z[2] = wy; z[3] = wz;
#pragma unroll
      for (int c = 4; c < 20; ++c) z[c] = 0.f;
      float o[20];
      compose20(z, o);
#pragma unroll
      for (int q = 0; q < 5; ++q)
        *((float4*)&S[wave][j][4 * q]) = ((float4*)o)[q];
    }
  }
#pragma unroll 1
  for (int L = 1; L <= 7; ++L) {
    const float* __restrict__ W = A.W[L];
    float2 acc[20];
#pragma unroll
    for (int c = 0; c < 20; ++c) acc[c] = make_float2(0.f, 0.f);
    for (int kb = 0; kb < HID; kb += KB) {
      __syncthreads();
      const float4* src = (const float4*)(W + kb * HID);
#pragma unroll
      for (int i = 0; i < (KB * HID / 4) / 256; ++i)
        ((float4*)Wt)[threadIdx.x + i * 256] = src[threadIdx.x + i * 256];
      __syncthreads();
#pragma unroll 4
      for (int k = 0; k < KB; ++k) {
        float s[20];
        const float4* srow = (const float4*)&S[wave][kb + k][0];
#pragma unroll
        for (int q = 0; q < 5; ++q) ((float4*)s)[q] = srow[q];
        const float2 w2 = *(const float2*)&Wt[k][j0];
#pragma unroll
        for (int c = 0; c < 20; ++c) {
          acc[c].x = fmaf(s[c], w2.x, acc[c].x);
          acc[c].y = fmaf(s[c], w2.y, acc[c].y);
        }
      }
    }
    const float* b = A.b[L];
    float za[20], zb[20];
#pragma unroll
    for (int c = 0; c < 20; ++c) { za[c] = acc[c].x; zb[c] = acc[c].y; }
    za[0] += b[j0];
    zb[0] += b[j0 + 1];
    float oa[20], ob[20];
    compose20(za, oa);
    compose20(zb, ob);
#pragma unroll
    for (int q = 0; q < 5; ++q) {
      *((float4*)&S[wave][j0][4 * q])     = ((float4*)oa)[q];
      *((float4*)&S[wave][j0 + 1][4 * q]) = ((float4*)ob)[q];
    }
  }
  {
    const float* W8 = A.W[8];
    float zc[20];
#pragma unroll
    for (int c = 0; c < 20; ++c) zc[c] = 0.f;
#pragma unroll
    for (int kk = 0; kk < 2; ++kk) {
      const int k = lane + kk * 64;
      const float w = W8[2 * k];
      float s[20];
      const float4* srow = (const float4*)&S[wave][k][0];
#pragma unroll
      for (int q = 0; q < 5; ++q) ((float4*)s)[q] = srow[q];
#pragma unroll
      for (int c = 0; c < 20; ++c) zc[c] = fmaf(s[c], w, zc[c]);
    }
#pragma unroll
    for (int off = 32; off; off >>= 1) {
#pragma unroll
      for (int c = 0; c < 20; ++c) zc[c] += __shfl_xor(zc[c], off, 64);
    }
    if (lane == 0) {
      zc[0] += A.b[8][0];
      float o[20];
      compose20(zc, o);
      const float u  =  o[2];
      const float vv = -o[1];
      const float ux =  o[5],  uy =  o[7],  ut =  o[8];
      const float vx = -o[4],  vy = -o[5],  vt = -o[6];
      const float uxx =  o[11], uyy =  o[16];
      const float vxx = -o[10], vyy = -o[13];
      const float l1 = A.lam1[0], l2 = A.lam2[0];
      const float fu = ut + l1 * (u * ux + vv * uy) - l2 * (uxx + uyy);
      const float fv = vt + l1 * (u * vx + vv * vy) - l2 * (vxx + vyy);
      A.out[p]            = u;
      A.out[NPTS + p]     = vv;
      A.out[2 * NPTS + p] = fu;
      A.out[3 * NPTS + p] = fv;
    }
  }
}

extern "C" void kernel_launch(void* const* d_in, const int* in_sizes, int n_in,
                              void* d_out, int out_size, void* d_ws, size_t ws_size,
                              hipStream_t stream) {
  PinnArgs A;
  A.x = (const float*)d_in[0];
  A.y = (const float*)d_in[1];
  A.t = (const float*)d_in[2];
  for (int i = 0; i < 9; ++i) {
    A.W[i] = (const float*)d_in[3 + 2 * i];
    A.b[i] = (const float*)d_in[4 + 2 * i];
  }
  A.lam1 = (const float*)d_in[21];
  A.lam2 = (const float*)d_in[22];
  A.out  = (float*)d_out;
  A.wt   = (const _Float16*)d_ws;

  const size_t need = (size_t)7 * 2 * 16384 * sizeof(_Float16);  // 458752 B
  if (ws_size >= need) {
    PrepArgs P;
    for (int L = 1; L <= 7; ++L) P.W[L - 1] = (const float*)d_in[3 + 2 * L];
    P.out = (_Float16*)d_ws;
    hipLaunchKernelGGL(prep_w16, dim3((7 * 16384) / 256), dim3(256), 0, stream, P);
    hipLaunchKernelGGL(pinn_mfma, dim3(NPTS / PPB), dim3(256), 0, stream, A);
  } else {
    hipLaunchKernelGGL(pinn_fp32, dim3(NPTS / 4), dim3(256), 0, stream, A);
  }
}

// Round 15
// 446.910 us; speedup vs baseline: 1.0743x; 1.0743x over previous
//
#include <hip/hip_runtime.h>
#include <math.h>

#define NPTS 32768
#define HID  128
#define PPB  4      // points per block; 13 channels padded to 16 rows each -> 64 M-rows
#define NCH  13
#define KB   32     // fp32 fallback K-block

typedef __attribute__((ext_vector_type(8))) _Float16 f16x8;
typedef __attribute__((ext_vector_type(4))) float f32x4;

struct PinnArgs {
  const float* x; const float* y; const float* t;
  const float* W[9]; const float* b[9];
  const float* lam1; const float* lam2;
  float* out;
  const _Float16* wt;   // [7 layers][2 planes hi/lo][128 n][128 k]
};

struct PrepArgs { const float* W[7]; _Float16* out; };

// ---- cross-lane 16/32 swaps (VALU permlane on gfx950; shfl fallback) ----
// Network (R9/R10 HW-verified): given per-lane a0..a3 with lane-quad kg,
// {swap16(a0,a1); swap16(a2,a3); swap32(a0,a2); swap32(a1,a3)} transposes the
// 4x4 (quad kg x array idx q) matrix: lane(kg,lr).z_i = lane(i,lr).a_kg.
__device__ __forceinline__ void swap16(float& a, float& b) {
#if __has_builtin(__builtin_amdgcn_permlane16_swap)
  auto r = __builtin_amdgcn_permlane16_swap(__float_as_uint(a), __float_as_uint(b), false, false);
  a = __uint_as_float(r[0]); b = __uint_as_float(r[1]);
#else
  const bool odd = (threadIdx.x >> 4) & 1;
  const float sa = __shfl_xor(a, 16, 64), sb = __shfl_xor(b, 16, 64);
  const float na = odd ? sb : a;
  const float nb = odd ? b : sa;
  a = na; b = nb;
#endif
}
__device__ __forceinline__ void swap32(float& a, float& b) {
#if __has_builtin(__builtin_amdgcn_permlane32_swap)
  auto r = __builtin_amdgcn_permlane32_swap(__float_as_uint(a), __float_as_uint(b), false, false);
  a = __uint_as_float(r[0]); b = __uint_as_float(r[1]);
#else
  const bool up = (threadIdx.x >> 5) & 1;
  const float sa = __shfl_xor(a, 32, 64), sb = __shfl_xor(b, 32, 64);
  const float na = up ? sb : a;
  const float nb = up ? b : sa;
  a = na; b = nb;
#endif
}

// Fast tanh (R11-exonerated: absmax bit-identical to libm tanhf run).
__device__ __forceinline__ float tanh_fast(float z) {
  const float zc = fminf(fmaxf(z, -15.f), 15.f);
  const float e  = __expf(2.f * zc);
  return 1.f - 2.f * __builtin_amdgcn_rcpf(e + 1.f);
}

// 13-channel Faa di Bruno composition of a = tanh(z).
// Channels: [0]=val, [1]=gx,[2]=gy,[3]=gt,
// [4]=Hxx,[5]=Hxy,[6]=Hxt,[7]=Hyy,[8]=Hyt,
// [9]=Txxx,[10]=Txxy,[11]=Txyy,[12]=Tyyy.  Closed set (R6-verified).
__device__ __forceinline__ void compose13(const float z[NCH], float o[NCH]) {
  const float v  = tanh_fast(z[0]);
  const float f1 = 1.f - v * v;
  const float f2 = -2.f * v * f1;
  const float f3 = f1 * (4.f * v * v - 2.f * f1);
  const float gx = z[1], gy = z[2], gt = z[3];
  const float hxx = z[4], hxy = z[5], hxt = z[6], hyy = z[7], hyt = z[8];
  o[0] = v;
  o[1] = f1 * gx; o[2] = f1 * gy; o[3] = f1 * gt;
  o[4] = f2 * gx * gx + f1 * hxx;
  o[5] = f2 * gx * gy + f1 * hxy;
  o[6] = f2 * gx * gt + f1 * hxt;
  o[7] = f2 * gy * gy + f1 * hyy;
  o[8] = f2 * gy * gt + f1 * hyt;
  o[9]  = f3 * gx * gx * gx + f2 * (3.f * hxx * gx)            + f1 * z[9];
  o[10] = f3 * gx * gx * gy + f2 * (hxx * gy + 2.f * hxy * gx) + f1 * z[10];
  o[11] = f3 * gx * gy * gy + f2 * (2.f * hxy * gy + hyy * gx) + f1 * z[11];
  o[12] = f3 * gy * gy * gy + f2 * (3.f * hyy * gy)            + f1 * z[12];
}

// Weight prep: W^T hi/lo f16 planes. wt[(L*2+plane)*16384 + n*128 + k]
__global__ __launch_bounds__(256) void prep_w16(PrepArgs P) {
  const int idx = blockIdx.x * 256 + threadIdx.x;
  if (idx >= 7 * 16384) return;
  const int L = idx >> 14;
  const int r = idx & 16383;
  const int n = r & 127;
  const int k = r >> 7;
  const float w = P.W[L][k * HID + n];
  const _Float16 hi = (_Float16)w;
  const _Float16 lo = (_Float16)(w - (float)hi);
  P.out[(size_t)(L * 2 + 0) * 16384 + n * 128 + k] = hi;
  P.out[(size_t)(L * 2 + 1) * 16384 + n * 128 + k] = lo;
}

// ---- A-plane column swizzle (R10/R11-proven layout) ----
// Physical 16B-block = logical block ^ rowhi (rowhi = row>>4). Bijective
// within a row -> bit-exact.
__device__ __forceinline__ int swz(int j, int rowhi) {
  return (((j >> 3) ^ rowhi) << 3) | (j & 7);
}

// R12 lesson: never set launch_bounds below natural VGPR. R14 lesson: FULL
// B double-buffer (128 VGPR of B) spills at the (256,4) cap (WRITE_SIZE
// 1MB->157MB). R15: prefetch only the hi plane (32 VGPR) — fits at ~100.
__global__ __launch_bounds__(256, 4) void pinn_mfma(PinnArgs A) {
  __shared__ _Float16 Ah[64][136];  // 17408 B hi plane; row = p*16+c
  __shared__ _Float16 Al[64][136];  // 17408 B lo plane
  const int tid  = threadIdx.x;
  const int wave = tid >> 6;
  const int lane = tid & 63;
  const int kg   = lane >> 4;   // 0..3
  const int lr   = lane & 15;   // 0..15
  const int pbase = blockIdx.x * PPB;

  // zero pad rows (c=13..15 of each point stripe); never rewritten
  if (tid < 136) {
#pragma unroll
    for (int pp = 0; pp < PPB; ++pp)
#pragma unroll
      for (int c = NCH; c < 16; ++c) {
        Ah[pp * 16 + c][tid] = (_Float16)0.f;
        Al[pp * 16 + c][tid] = (_Float16)0.f;
      }
  }

  // ---------- layer 0: 3 -> 128 ----------
  for (int t = tid; t < PPB * HID; t += 256) {
    const int p = t >> 7, j = t & 127;
    const int gp = pbase + p;
    const float xv = A.x[gp], yv = A.y[gp], tv = A.t[gp];
    const float wx = A.W[0][j], wy = A.W[0][HID + j], wz = A.W[0][2 * HID + j];
    float z[NCH], o[NCH];
    z[0] = fmaf(wx, xv, fmaf(wy, yv, fmaf(wz, tv, A.b[0][j])));
    z[1] = wx; z[2] = wy; z[3] = wz;
#pragma unroll
    for (int c = 4; c < NCH; ++c) z[c] = 0.f;
    compose13(z, o);
    const int pj = swz(j, p);
#pragma unroll
    for (int c = 0; c < NCH; ++c) {
      const _Float16 hi = (_Float16)o[c];
      Ah[p * 16 + c][pj] = hi;
      Al[p * 16 + c][pj] = (_Float16)(o[c] - (float)hi);
    }
  }
  __syncthreads();

#define LOADB8(D, WP)                                                         \
  {                                                                           \
    _Pragma("unroll")                                                         \
    for (int nt = 0; nt < 2; ++nt) {                                          \
      const int col = wave * 32 + nt * 16 + lr;                               \
      _Pragma("unroll")                                                       \
      for (int ks = 0; ks < 4; ++ks)                                          \
        D[nt][ks] = *(const f16x8*)((WP) + col * 128 + ks * 32 + kg * 8);     \
    }                                                                         \
  }

  // ---------- layers 1..7: GEMM + permlane transpose; bh half-prefetch ----
  f16x8 bh[2][2][4];   // double-buffered hi plane (32 VGPR per buffer)
  LOADB8(bh[0], A.wt);

#pragma unroll
  for (int L = 1; L <= 7; ++L) {
    const int cur = (L - 1) & 1, nxt = L & 1;
    const _Float16* __restrict__ WL_ = A.wt + ((size_t)(L - 1) * 2 + 1) * 16384;
    f16x8 bl[2][4];
    LOADB8(bl, WL_);   // lo plane loaded per layer (exposed; half the bytes)

    f32x4 acc[4][2];   // [m][nt]; m-tile == point m (16 rows/point)
#pragma unroll
    for (int m = 0; m < 4; ++m)
#pragma unroll
      for (int nt = 0; nt < 2; ++nt) acc[m][nt] = (f32x4)(0.f);

#pragma unroll
    for (int ks = 0; ks < 4; ++ks) {
#pragma unroll
      for (int m = 0; m < 4; ++m) {
        const int row = m * 16 + lr;
        // logical 16B-block 4ks+kg at rowhi==m -> phys 4ks + (kg^m)
        const int kb = (4 * ks + (kg ^ m)) * 8;
        const f16x8 ah = *(const f16x8*)&Ah[row][kb];
        const f16x8 al = *(const f16x8*)&Al[row][kb];
#pragma unroll
        for (int nt = 0; nt < 2; ++nt) {
          acc[m][nt] = __builtin_amdgcn_mfma_f32_16x16x32_f16(ah, bh[cur][nt][ks], acc[m][nt], 0, 0, 0);
          acc[m][nt] = __builtin_amdgcn_mfma_f32_16x16x32_f16(ah, bl[nt][ks], acc[m][nt], 0, 0, 0);
          acc[m][nt] = __builtin_amdgcn_mfma_f32_16x16x32_f16(al, bh[cur][nt][ks], acc[m][nt], 0, 0, 0);
        }
      }
    }

    // prefetch next layer's hi B (consumed after two barriers — hidden)
    if (L < 7) {
      const _Float16* WHn = A.wt + (size_t)L * 2 * 16384;
      LOADB8(bh[nxt], WHn);
    }

    // ---- in-register 4x4 quad transpose across m (no Z LDS round-trip) ----
    const float* __restrict__ bb = A.b[L];
    float oo[2][NCH];
#pragma unroll
    for (int nt = 0; nt < 2; ++nt) {
      float z[16];
#pragma unroll
      for (int r = 0; r < 4; ++r) {
        float a0 = acc[0][nt][r], a1 = acc[1][nt][r];
        float a2 = acc[2][nt][r], a3 = acc[3][nt][r];
        swap16(a0, a1); swap16(a2, a3);
        swap32(a0, a2); swap32(a1, a3);
        z[0 + r] = a0; z[4 + r] = a1; z[8 + r] = a2; z[12 + r] = a3;
      }
      z[0] += bb[wave * 32 + nt * 16 + lr];
      compose13(z, oo[nt]);
    }

    __syncthreads();   // all waves' A-fragment LDS reads complete
#pragma unroll
    for (int nt = 0; nt < 2; ++nt) {
      const int j  = wave * 32 + nt * 16 + lr;
      const int pj = swz(j, kg);        // rowhi == kg for rows kg*16+c
#pragma unroll
      for (int c = 0; c < NCH; ++c) {
        const _Float16 hi = (_Float16)oo[nt][c];
        Ah[kg * 16 + c][pj] = hi;
        Al[kg * 16 + c][pj] = (_Float16)(oo[nt][c] - (float)hi);
      }
    }
    __syncthreads();   // new activations visible before next layer's reads
  }
#undef LOADB8

  // ---------- layer 8 (column 0) + outputs ----------
  {
    const int p = wave, gp = pbase + p;
    const float w0 = A.W[8][2 * lane];
    const float w1 = A.W[8][2 * (lane + 64)];
    const int pj0 = swz(lane, p);
    const int pj1 = swz(lane + 64, p);
    float zc[NCH];
#pragma unroll
    for (int c = 0; c < NCH; ++c) {
      const int rr = p * 16 + c;
      const float s0 = (float)Ah[rr][pj0] + (float)Al[rr][pj0];
      const float s1 = (float)Ah[rr][pj1] + (float)Al[rr][pj1];
      zc[c] = fmaf(s0, w0, s1 * w1);
    }
#pragma unroll
    for (int off = 32; off; off >>= 1) {
#pragma unroll
      for (int c = 0; c < NCH; ++c) zc[c] += __shfl_xor(zc[c], off, 64);
    }
    if (lane == 0) {
      zc[0] += A.b[8][0];
      float o[NCH];
      compose13(zc, o);
      const float u  =  o[2];            // psi_y
      const float vv = -o[1];            // -psi_x
      const float ux =  o[5],  uy =  o[7],  ut =  o[8];
      const float vx = -o[4],  vy = -o[5],  vt = -o[6];
      const float uxx =  o[10], uyy =  o[12];
      const float vxx = -o[9],  vyy = -o[11];
      const float l1 = A.lam1[0], l2 = A.lam2[0];
      const float fu = ut + l1 * (u * ux + vv * uy) - l2 * (uxx + uyy);
      const float fv = vt + l1 * (u * vx + vv * vy) - l2 * (vxx + vyy);
      A.out[gp]            = u;
      A.out[NPTS + gp]     = vv;
      A.out[2 * NPTS + gp] = fu;
      A.out[3 * NPTS + gp] = fv;
    }
  }
}

// ---------------- fp32 fallback (proven round-1 kernel, 20-channel) ----------------
__device__ __forceinline__ void compose20(const float z[20], float o[20]) {
  const float v  = tanhf(z[0]);
  const float f1 = 1.f - v * v;
  const float f2 = -2.f * v * f1;
  const float f3 = f1 * (4.f * v * v - 2.f * f1);
  const float gx = z[1], gy = z[2], gt = z[3];
  const float hxx = z[4], hxy = z[5], hxz = z[6], hyy = z[7], hyz = z[8], hzz = z[9];
  o[0] = v;
  o[1] = f1 * gx; o[2] = f1 * gy; o[3] = f1 * gt;
  o[4] = f2 * gx * gx + f1 * hxx;
  o[5] = f2 * gx * gy + f1 * hxy;
  o[6] = f2 * gx * gt + f1 * hxz;
  o[7] = f2 * gy * gy + f1 * hyy;
  o[8] = f2 * gy * gt + f1 * hyz;
  o[9] = f2 * gt * gt + f1 * hzz;
  o[10] = f3 * gx * gx * gx + f2 * (3.f * hxx * gx)                 + f1 * z[10];
  o[11] = f3 * gx * gx * gy + f2 * (hxx * gy + 2.f * hxy * gx)      + f1 * z[11];
  o[12] = f3 * gx * gx * gt + f2 * (hxx * gt + 2.f * hxz * gx)      + f1 * z[12];
  o[13] = f3 * gx * gy * gy + f2 * (2.f * hxy * gy + hyy * gx)      + f1 * z[13];
  o[14] = f3 * gx * gy * gt + f2 * (hxy * gt + hxz * gy + hyz * gx) + f1 * z[14];
  o[15] = f3 * gx * gt * gt + f2 * (2.f * hxz * gt + hzz * gx)      + f1 * z[15];
  o[16] = f3 * gy * gy * gy + f2 * (3.f * hyy * gy)                 + f1 * z[16];
  o[17] = f3 * gy * gy * gt + f2 * (hyy * gt + 2.f * hyz * gy)      + f1 * z[17];
  o[18] = f3 * gy * gt * gt + f2 * (2.f * hyz * gt + hzz * gy)      + f1 * z[18];
  o[19] = f3 * gt * gt * gt + f2 * (3.f * hzz * gt)                 + f1 * z[19];
}

__global__ __launch_bounds__(256) void pinn_fp32(PinnArgs A) {
  __shared__ float S[4][HID][20];
  __shared__ float Wt[KB][HID];
  const int wave = threadIdx.x >> 6;
  const int lane = threadIdx.x & 63;
  const int p    = blockIdx.x * 4 + wave;
  const int j0   = lane * 2;
  {
    const float xv = A.x[p], yv = A.y[p], tv = A.t[p];
    const float* W0 = A.W[0];
    const float* b0 = A.b[0];
#pragma unroll
    for (int jj = 0; jj < 2; ++jj) {
      const int j = j0 + jj;
      const float wx = W0[j], wy = W0[HID + j], wz = W0[2 * HID + j];
      float z[20];
      z[0] = fmaf(wx, xv, fmaf(wy, yv, fmaf(wz, tv, b0[j])));
      z[1] = wx; z[2] = wy; z[3] = wz;
#pragma unroll
      for (int c = 4; c < 20; ++c) z[c] = 0.f;
      float o[20];
      compose20(z, o);
#pragma unroll
      for (int q = 0; q < 5; ++q)
        *((float4*)&S[wave][j][4 * q]) = ((float4*)o)[q];
    }
  }
#pragma unroll 1
  for (int L = 1; L <= 7; ++L) {
    const float* __restrict__ W = A.W[L];
    float2 acc[20];
#pragma unroll
    for (int c = 0; c < 20; ++c) acc[c] = make_float2(0.f, 0.f);
    for (int kb = 0; kb < HID; kb += KB) {
      __syncthreads();
      const float4* src = (const float4*)(W + kb * HID);
#pragma unroll
      for (int i = 0; i < (KB * HID / 4) / 256; ++i)
        ((float4*)Wt)[threadIdx.x + i * 256] = src[threadIdx.x + i * 256];
      __syncthreads();
#pragma unroll 4
      for (int k = 0; k < KB; ++k) {
        float s[20];
        const float4* srow = (const float4*)&S[wave][kb + k][0];
#pragma unroll
        for (int q = 0; q < 5; ++q) ((float4*)s)[q] = srow[q];
        const float2 w2 = *(const float2*)&Wt[k][j0];
#pragma unroll
        for (int c = 0; c < 20; ++c) {
          acc[c].x = fmaf(s[c], w2.x, acc[c].x);
          acc[c].y = fmaf(s[c], w2.y, acc[c].y);
        }
      }
    }
    const float* b = A.b[L];
    float za[20], zb[20];
#pragma unroll
    for (int c = 0; c < 20; ++c) { za[c] = acc[c].x; zb[c] = acc[c].y; }
    za[0] += b[j0];
    zb[0] += b[j0 + 1];
    float oa[20], ob[20];
    compose20(za, oa);
    compose20(zb, ob);
#pragma unroll
    for (int q = 0; q < 5; ++q) {
      *((float4*)&S[wave][j0][4 * q])     = ((float4*)oa)[q];
      *((float4*)&S[wave][j0 + 1][4 * q]) = ((float4*)ob)[q];
    }
  }
  {
    const float* W8 = A.W[8];
    float zc[20];
#pragma unroll
    for (int c = 0; c < 20; ++c) zc[c] = 0.f;
#pragma unroll
    for (int kk = 0; kk < 2; ++kk) {
      const int k = lane + kk * 64;
      const float w = W8[2 * k];
      float s[20];
      const float4* srow = (const float4*)&S[wave][k][0];
#pragma unroll
      for (int q = 0; q < 5; ++q) ((float4*)s)[q] = srow[q];
#pragma unroll
      for (int c = 0; c < 20; ++c) zc[c] = fmaf(s[c], w, zc[c]);
    }
#pragma unroll
    for (int off = 32; off; off >>= 1) {
#pragma unroll
      for (int c = 0; c < 20; ++c) zc[c] += __shfl_xor(zc[c], off, 64);
    }
    if (lane == 0) {
      zc[0] += A.b[8][0];
      float o[20];
      compose20(zc, o);
      const float u  =  o[2];
      const float vv = -o[1];
      const float ux =  o[5],  uy =  o[7],  ut =  o[8];
      const float vx = -o[4],  vy = -o[5],  vt = -o[6];
      const float uxx =  o[11], uyy =  o[16];
      const float vxx = -o[10], vyy = -o[13];
      const float l1 = A.lam1[0], l2 = A.lam2[0];
      const float fu = ut + l1 * (u * ux + vv * uy) - l2 * (uxx + uyy);
      const float fv = vt + l1 * (u * vx + vv * vy) - l2 * (vxx + vyy);
      A.out[p]            = u;
      A.out[NPTS + p]     = vv;
      A.out[2 * NPTS + p] = fu;
      A.out[3 * NPTS + p] = fv;
    }
  }
}

extern "C" void kernel_launch(void* const* d_in, const int* in_sizes, int n_in,
                              void* d_out, int out_size, void* d_ws, size_t ws_size,
                              hipStream_t stream) {
  PinnArgs A;
  A.x = (const float*)d_in[0];
  A.y = (const float*)d_in[1];
  A.t = (const float*)d_in[2];
  for (int i = 0; i < 9; ++i) {
    A.W[i] = (const float*)d_in[3 + 2 * i];
    A.b[i] = (const float*)d_in[4 + 2 * i];
  }
  A.lam1 = (const float*)d_in[21];
  A.lam2 = (const float*)d_in[22];
  A.out  = (float*)d_out;
  A.wt   = (const _Float16*)d_ws;

  const size_t need = (size_t)7 * 2 * 16384 * sizeof(_Float16);  // 458752 B
  if (ws_size >= need) {
    PrepArgs P;
    for (int L = 1; L <= 7; ++L) P.W[L - 1] = (const float*)d_in[3 + 2 * L];
    P.out = (_Float16*)d_ws;
    hipLaunchKernelGGL(prep_w16, dim3((7 * 16384) / 256), dim3(256), 0, stream, P);
    hipLaunchKernelGGL(pinn_mfma, dim3(NPTS / PPB), dim3(256), 0, stream, A);
  } else {
    hipLaunchKernelGGL(pinn_fp32, dim3(NPTS / 4), dim3(256), 0, stream, A);
  }
}

// Round 16
// 435.441 us; speedup vs baseline: 1.1026x; 1.0263x over previous
//
#include <hip/hip_runtime.h>
#include <math.h>

#define NPTS 32768
#define HID  128
#define PPB  4      // points per block; 13 channels padded to 16 rows each -> 64 M-rows
#define NCH  13
#define KB   32     // fp32 fallback K-block

typedef __attribute__((ext_vector_type(8))) _Float16 f16x8;
typedef __attribute__((ext_vector_type(2))) _Float16 f16x2;
typedef __attribute__((ext_vector_type(4))) float f32x4;

struct PinnArgs {
  const float* x; const float* y; const float* t;
  const float* W[9]; const float* b[9];
  const float* lam1; const float* lam2;
  float* out;
  const _Float16* wt;   // [7 layers][2 planes hi/lo][128 n][128 k]
};

struct PrepArgs { const float* W[7]; _Float16* out; };

// ---- cross-lane 16/32 swaps (VALU permlane on gfx950; shfl fallback) ----
// Network (R9/R10 HW-verified): given per-lane a0..a3 with lane-quad kg,
// {swap16(a0,a1); swap16(a2,a3); swap32(a0,a2); swap32(a1,a3)} transposes the
// 4x4 (quad kg x array idx q) matrix: lane(kg,lr).z_i = lane(i,lr).a_kg.
__device__ __forceinline__ void swap16(float& a, float& b) {
#if __has_builtin(__builtin_amdgcn_permlane16_swap)
  auto r = __builtin_amdgcn_permlane16_swap(__float_as_uint(a), __float_as_uint(b), false, false);
  a = __uint_as_float(r[0]); b = __uint_as_float(r[1]);
#else
  const bool odd = (threadIdx.x >> 4) & 1;
  const float sa = __shfl_xor(a, 16, 64), sb = __shfl_xor(b, 16, 64);
  const float na = odd ? sb : a;
  const float nb = odd ? b : sa;
  a = na; b = nb;
#endif
}
__device__ __forceinline__ void swap32(float& a, float& b) {
#if __has_builtin(__builtin_amdgcn_permlane32_swap)
  auto r = __builtin_amdgcn_permlane32_swap(__float_as_uint(a), __float_as_uint(b), false, false);
  a = __uint_as_float(r[0]); b = __uint_as_float(r[1]);
#else
  const bool up = (threadIdx.x >> 5) & 1;
  const float sa = __shfl_xor(a, 32, 64), sb = __shfl_xor(b, 32, 64);
  const float na = up ? sb : a;
  const float nb = up ? b : sa;
  a = na; b = nb;
#endif
}

// Fast tanh (R11-exonerated: absmax bit-identical to libm tanhf run).
__device__ __forceinline__ float tanh_fast(float z) {
  const float zc = fminf(fmaxf(z, -15.f), 15.f);
  const float e  = __expf(2.f * zc);
  return 1.f - 2.f * __builtin_amdgcn_rcpf(e + 1.f);
}

// 13-channel Faa di Bruno composition of a = tanh(z).
// Channels: [0]=val, [1]=gx,[2]=gy,[3]=gt,
// [4]=Hxx,[5]=Hxy,[6]=Hxt,[7]=Hyy,[8]=Hyt,
// [9]=Txxx,[10]=Txxy,[11]=Txyy,[12]=Tyyy.  Closed set (R6-verified).
__device__ __forceinline__ void compose13(const float z[NCH], float o[NCH]) {
  const float v  = tanh_fast(z[0]);
  const float f1 = 1.f - v * v;
  const float f2 = -2.f * v * f1;
  const float f3 = f1 * (4.f * v * v - 2.f * f1);
  const float gx = z[1], gy = z[2], gt = z[3];
  const float hxx = z[4], hxy = z[5], hxt = z[6], hyy = z[7], hyt = z[8];
  o[0] = v;
  o[1] = f1 * gx; o[2] = f1 * gy; o[3] = f1 * gt;
  o[4] = f2 * gx * gx + f1 * hxx;
  o[5] = f2 * gx * gy + f1 * hxy;
  o[6] = f2 * gx * gt + f1 * hxt;
  o[7] = f2 * gy * gy + f1 * hyy;
  o[8] = f2 * gy * gt + f1 * hyt;
  o[9]  = f3 * gx * gx * gx + f2 * (3.f * hxx * gx)            + f1 * z[9];
  o[10] = f3 * gx * gx * gy + f2 * (hxx * gy + 2.f * hxy * gx) + f1 * z[10];
  o[11] = f3 * gx * gy * gy + f2 * (2.f * hxy * gy + hyy * gx) + f1 * z[11];
  o[12] = f3 * gy * gy * gy + f2 * (3.f * hyy * gy)            + f1 * z[12];
}

// Weight prep: W^T hi/lo f16 planes. wt[(L*2+plane)*16384 + n*128 + k].
// R16: B-tile position (w,nt,lr) = phys col n computes ORIGINAL neuron
// sigma(n) = (n&96) | 2*(n&15) | ((n>>4)&1), so a lane's nt=0/1 compose
// outputs land in ADJACENT LDS cols (packed f16x2 writes). A-storage stays
// identity (col p holds neuron p) -> k-dim, layer 0 and layer 8 untouched.
__global__ __launch_bounds__(256) void prep_w16(PrepArgs P) {
  const int idx = blockIdx.x * 256 + threadIdx.x;
  if (idx >= 7 * 16384) return;
  const int L = idx >> 14;
  const int r = idx & 16383;
  const int n = r & 127;
  const int k = r >> 7;
  const int nl = (n & 96) | ((n & 15) << 1) | ((n >> 4) & 1);
  const float w = P.W[L][k * HID + nl];
  const _Float16 hi = (_Float16)w;
  const _Float16 lo = (_Float16)(w - (float)hi);
  P.out[(size_t)(L * 2 + 0) * 16384 + n * 128 + k] = hi;
  P.out[(size_t)(L * 2 + 1) * 16384 + n * 128 + k] = lo;
}

// ---- A-plane column swizzle, R16 form ----
// phys 16B-block = logical ^ (rowhi<<2).  Row-block stride 16*272B == 0 mod
// 32 banks, so without kg entering the HIGH block bits all 4 kg-quads'
// compose writes land in one 4-block bank run (R10-R15: conflicts pinned at
// 5.3e7). ^(rowhi<<2) spreads writer quads across all 16 blocks; GEMM reads
// become kb = 4*(ks^m)+kg (same bank structure as before). Bijective.
__device__ __forceinline__ int swz(int j, int rowhi) {
  return ((((j >> 3) ^ (rowhi << 2)) & 15) << 3) | (j & 7);
}

// R12 lesson: never set launch_bounds below natural VGPR. R14 lesson: FULL
// B double-buffer spills. R15: hi-plane-only prefetch fits (proven 518us).
__global__ __launch_bounds__(256, 4) void pinn_mfma(PinnArgs A) {
  __shared__ _Float16 Ah[64][136];  // 17408 B hi plane; row = p*16+c
  __shared__ _Float16 Al[64][136];  // 17408 B lo plane
  const int tid  = threadIdx.x;
  const int wave = tid >> 6;
  const int lane = tid & 63;
  const int kg   = lane >> 4;   // 0..3
  const int lr   = lane & 15;   // 0..15
  const int pbase = blockIdx.x * PPB;

  // zero pad rows (c=13..15 of each point stripe); never rewritten
  if (tid < 136) {
#pragma unroll
    for (int pp = 0; pp < PPB; ++pp)
#pragma unroll
      for (int c = NCH; c < 16; ++c) {
        Ah[pp * 16 + c][tid] = (_Float16)0.f;
        Al[pp * 16 + c][tid] = (_Float16)0.f;
      }
  }

  // ---------- layer 0: 3 -> 128 ----------
  for (int t = tid; t < PPB * HID; t += 256) {
    const int p = t >> 7, j = t & 127;
    const int gp = pbase + p;
    const float xv = A.x[gp], yv = A.y[gp], tv = A.t[gp];
    const float wx = A.W[0][j], wy = A.W[0][HID + j], wz = A.W[0][2 * HID + j];
    float z[NCH], o[NCH];
    z[0] = fmaf(wx, xv, fmaf(wy, yv, fmaf(wz, tv, A.b[0][j])));
    z[1] = wx; z[2] = wy; z[3] = wz;
#pragma unroll
    for (int c = 4; c < NCH; ++c) z[c] = 0.f;
    compose13(z, o);
    const int pj = swz(j, p);
#pragma unroll
    for (int c = 0; c < NCH; ++c) {
      const _Float16 hi = (_Float16)o[c];
      Ah[p * 16 + c][pj] = hi;
      Al[p * 16 + c][pj] = (_Float16)(o[c] - (float)hi);
    }
  }
  __syncthreads();

#define LOADB8(D, WP)                                                         \
  {                                                                           \
    _Pragma("unroll")                                                         \
    for (int nt = 0; nt < 2; ++nt) {                                          \
      const int col = wave * 32 + nt * 16 + lr;                               \
      _Pragma("unroll")                                                       \
      for (int ks = 0; ks < 4; ++ks)                                          \
        D[nt][ks] = *(const f16x8*)((WP) + col * 128 + ks * 32 + kg * 8);     \
    }                                                                         \
  }

  // ---------- layers 1..7: GEMM + permlane transpose; bh half-prefetch ----
  f16x8 bh[2][2][4];   // double-buffered hi plane (32 VGPR per buffer)
  LOADB8(bh[0], A.wt);

#pragma unroll
  for (int L = 1; L <= 7; ++L) {
    const int cur = (L - 1) & 1, nxt = L & 1;
    const _Float16* __restrict__ WL_ = A.wt + ((size_t)(L - 1) * 2 + 1) * 16384;
    f16x8 bl[2][4];
    LOADB8(bl, WL_);   // lo plane loaded per layer (exposed; half the bytes)

    f32x4 acc[4][2];   // [m][nt]; m-tile == point m (16 rows/point)
#pragma unroll
    for (int m = 0; m < 4; ++m)
#pragma unroll
      for (int nt = 0; nt < 2; ++nt) acc[m][nt] = (f32x4)(0.f);

#pragma unroll
    for (int ks = 0; ks < 4; ++ks) {
#pragma unroll
      for (int m = 0; m < 4; ++m) {
        const int row = m * 16 + lr;
        // logical block 4ks+kg at rowhi==m -> phys 4*(ks^m)+kg
        const int kb = (4 * (ks ^ m) + kg) * 8;
        const f16x8 ah = *(const f16x8*)&Ah[row][kb];
        const f16x8 al = *(const f16x8*)&Al[row][kb];
#pragma unroll
        for (int nt = 0; nt < 2; ++nt) {
          acc[m][nt] = __builtin_amdgcn_mfma_f32_16x16x32_f16(ah, bh[cur][nt][ks], acc[m][nt], 0, 0, 0);
          acc[m][nt] = __builtin_amdgcn_mfma_f32_16x16x32_f16(ah, bl[nt][ks], acc[m][nt], 0, 0, 0);
          acc[m][nt] = __builtin_amdgcn_mfma_f32_16x16x32_f16(al, bh[cur][nt][ks], acc[m][nt], 0, 0, 0);
        }
      }
    }

    // prefetch next layer's hi B (consumed after two barriers — hidden)
    if (L < 7) {
      const _Float16* WHn = A.wt + (size_t)L * 2 * 16384;
      LOADB8(bh[nxt], WHn);
    }

    // ---- in-register 4x4 quad transpose across m (no Z LDS round-trip) ----
    // Tile (nt,lr) = neuron wave*32 + 2*lr + nt (prep_w16 sigma), so the two
    // nt outputs are adjacent neurons -> packed f16x2 LDS writes below.
    const float* __restrict__ bb = A.b[L];
    const float2 bj2 = *(const float2*)&bb[wave * 32 + 2 * lr];
    float oo[2][NCH];
#pragma unroll
    for (int nt = 0; nt < 2; ++nt) {
      float z[16];
#pragma unroll
      for (int r = 0; r < 4; ++r) {
        float a0 = acc[0][nt][r], a1 = acc[1][nt][r];
        float a2 = acc[2][nt][r], a3 = acc[3][nt][r];
        swap16(a0, a1); swap16(a2, a3);
        swap32(a0, a2); swap32(a1, a3);
        z[0 + r] = a0; z[4 + r] = a1; z[8 + r] = a2; z[12 + r] = a3;
      }
      z[0] += nt ? bj2.y : bj2.x;
      compose13(z, oo[nt]);
    }

    __syncthreads();   // all waves' A-fragment LDS reads complete
    {
      const int j0  = wave * 32 + 2 * lr;                 // even
      const int off = ((((j0 >> 3) ^ (kg << 2)) & 15) << 3) | (j0 & 7);
#pragma unroll
      for (int c = 0; c < NCH; ++c) {
        f16x2 h, l;
        h[0] = (_Float16)oo[0][c];
        h[1] = (_Float16)oo[1][c];
        l[0] = (_Float16)(oo[0][c] - (float)h[0]);
        l[1] = (_Float16)(oo[1][c] - (float)h[1]);
        *(f16x2*)&Ah[kg * 16 + c][off] = h;
        *(f16x2*)&Al[kg * 16 + c][off] = l;
      }
    }
    __syncthreads();   // new activations visible before next layer's reads
  }
#undef LOADB8

  // ---------- layer 8 (column 0) + outputs ----------
  {
    const int p = wave, gp = pbase + p;
    const float w0 = A.W[8][2 * lane];
    const float w1 = A.W[8][2 * (lane + 64)];
    const int pj0 = swz(lane, p);
    const int pj1 = swz(lane + 64, p);
    float zc[NCH];
#pragma unroll
    for (int c = 0; c < NCH; ++c) {
      const int rr = p * 16 + c;
      const float s0 = (float)Ah[rr][pj0] + (float)Al[rr][pj0];
      const float s1 = (float)Ah[rr][pj1] + (float)Al[rr][pj1];
      zc[c] = fmaf(s0, w0, s1 * w1);
    }
#pragma unroll
    for (int off = 32; off; off >>= 1) {
#pragma unroll
      for (int c = 0; c < NCH; ++c) zc[c] += __shfl_xor(zc[c], off, 64);
    }
    if (lane == 0) {
      zc[0] += A.b[8][0];
      float o[NCH];
      compose13(zc, o);
      const float u  =  o[2];            // psi_y
      const float vv = -o[1];            // -psi_x
      const float ux =  o[5],  uy =  o[7],  ut =  o[8];
      const float vx = -o[4],  vy = -o[5],  vt = -o[6];
      const float uxx =  o[10], uyy =  o[12];
      const float vxx = -o[9],  vyy = -o[11];
      const float l1 = A.lam1[0], l2 = A.lam2[0];
      const float fu = ut + l1 * (u * ux + vv * uy) - l2 * (uxx + uyy);
      const float fv = vt + l1 * (u * vx + vv * vy) - l2 * (vxx + vyy);
      A.out[gp]            = u;
      A.out[NPTS + gp]     = vv;
      A.out[2 * NPTS + gp] = fu;
      A.out[3 * NPTS + gp] = fv;
    }
  }
}

// ---------------- fp32 fallback (proven round-1 kernel, 20-channel) ----------------
__device__ __forceinline__ void compose20(const float z[20], float o[20]) {
  const float v  = tanhf(z[0]);
  const float f1 = 1.f - v * v;
  const float f2 = -2.f * v * f1;
  const float f3 = f1 * (4.f * v * v - 2.f * f1);
  const float gx = z[1], gy = z[2], gt = z[3];
  const float hxx = z[4], hxy = z[5], hxz = z[6], hyy = z[7], hyz = z[8], hzz = z[9];
  o[0] = v;
  o[1] = f1 * gx; o[2] = f1 * gy; o[3] = f1 * gt;
  o[4] = f2 * gx * gx + f1 * hxx;
  o[5] = f2 * gx * gy + f1 * hxy;
  o[6] = f2 * gx * gt + f1 * hxz;
  o[7] = f2 * gy * gy + f1 * hyy;
  o[8] = f2 * gy * gt + f1 * hyz;
  o[9] = f2 * gt * gt + f1 * hzz;
  o[10] = f3 * gx * gx * gx + f2 * (3.f * hxx * gx)                 + f1 * z[10];
  o[11] = f3 * gx * gx * gy + f2 * (hxx * gy + 2.f * hxy * gx)      + f1 * z[11];
  o[12] = f3 * gx * gx * gt + f2 * (hxx * gt + 2.f * hxz * gx)      + f1 * z[12];
  o[13] = f3 * gx * gy * gy + f2 * (2.f * hxy * gy + hyy * gx)      + f1 * z[13];
  o[14] = f3 * gx * gy * gt + f2 * (hxy * gt + hxz * gy + hyz * gx) + f1 * z[14];
  o[15] = f3 * gx * gt * gt + f2 * (2.f * hxz * gt + hzz * gx)      + f1 * z[15];
  o[16] = f3 * gy * gy * gy + f2 * (3.f * hyy * gy)                 + f1 * z[16];
  o[17] = f3 * gy * gy * gt + f2 * (hyy * gt + 2.f * hyz * gy)      + f1 * z[17];
  o[18] = f3 * gy * gt * gt + f2 * (2.f * hyz * gt + hzz * gy)      + f1 * z[18];
  o[19] = f3 * gt * gt * gt + f2 * (3.f * hzz * gt)                 + f1 * z[19];
}

__global__ __launch_bounds__(256) void pinn_fp32(PinnArgs A) {
  __shared__ float S[4][HID][20];
  __shared__ float Wt[KB][HID];
  const int wave = threadIdx.x >> 6;
  const int lane = threadIdx.x & 63;
  const int p    = blockIdx.x * 4 + wave;
  const int j0   = lane * 2;
  {
    const float xv = A.x[p], yv = A.y[p], tv = A.t[p];
    const float* W0 = A.W[0];
    const float* b0 = A.b[0];
#pragma unroll
    for (int jj = 0; jj < 2; ++jj) {
      const int j = j0 + jj;
      const float wx = W0[j], wy = W0[HID + j], wz = W0[2 * HID + j];
      float z[20];
      z[0] = fmaf(wx, xv, fmaf(wy, yv, fmaf(wz, tv, b0[j])));
      z[1] = wx; z[2] = wy; z[3] = wz;
#pragma unroll
      for (int c = 4; c < 20; ++c) z[c] = 0.f;
      float o[20];
      compose20(z, o);
#pragma unroll
      for (int q = 0; q < 5; ++q)
        *((float4*)&S[wave][j][4 * q]) = ((float4*)o)[q];
    }
  }
#pragma unroll 1
  for (int L = 1; L <= 7; ++L) {
    const float* __restrict__ W = A.W[L];
    float2 acc[20];
#pragma unroll
    for (int c = 0; c < 20; ++c) acc[c] = make_float2(0.f, 0.f);
    for (int kb = 0; kb < HID; kb += KB) {
      __syncthreads();
      const float4* src = (const float4*)(W + kb * HID);
#pragma unroll
      for (int i = 0; i < (KB * HID / 4) / 256; ++i)
        ((float4*)Wt)[threadIdx.x + i * 256] = src[threadIdx.x + i * 256];
      __syncthreads();
#pragma unroll 4
      for (int k = 0; k < KB; ++k) {
        float s[20];
        const float4* srow = (const float4*)&S[wave][kb + k][0];
#pragma unroll
        for (int q = 0; q < 5; ++q) ((float4*)s)[q] = srow[q];
        const float2 w2 = *(const float2*)&Wt[k][j0];
#pragma unroll
        for (int c = 0; c < 20; ++c) {
          acc[c].x = fmaf(s[c], w2.x, acc[c].x);
          acc[c].y = fmaf(s[c], w2.y, acc[c].y);
        }
      }
    }
    const float* b = A.b[L];
    float za[20], zb[20];
#pragma unroll
    for (int c = 0; c < 20; ++c) { za[c] = acc[c].x; zb[c] = acc[c].y; }
    za[0] += b[j0];
    zb[0] += b[j0 + 1];
    float oa[20], ob[20];
    compose20(za, oa);
    compose20(zb, ob);
#pragma unroll
    for (int q = 0; q < 5; ++q) {
      *((float4*)&S[wave][j0][4 * q])     = ((float4*)oa)[q];
      *((float4*)&S[wave][j0 + 1][4 * q]) = ((float4*)ob)[q];
    }
  }
  {
    const float* W8 = A.W[8];
    float zc[20];
#pragma unroll
    for (int c = 0; c < 20; ++c) zc[c] = 0.f;
#pragma unroll
    for (int kk = 0; kk < 2; ++kk) {
      const int k = lane + kk * 64;
      const float w = W8[2 * k];
      float s[20];
      const float4* srow = (const float4*)&S[wave][k][0];
#pragma unroll
      for (int q = 0; q < 5; ++q) ((float4*)s)[q] = srow[q];
#pragma unroll
      for (int c = 0; c < 20; ++c) zc[c] = fmaf(s[c], w, zc[c]);
    }
#pragma unroll
    for (int off = 32; off; off >>= 1) {
#pragma unroll
      for (int c = 0; c < 20; ++c) zc[c] += __shfl_xor(zc[c], off, 64);
    }
    if (lane == 0) {
      zc[0] += A.b[8][0];
      float o[20];
      compose20(zc, o);
      const float u  =  o[2];
      const float vv = -o[1];
      const float ux =  o[5],  uy =  o[7],  ut =  o[8];
      const float vx = -o[4],  vy = -o[5],  vt = -o[6];
      const float uxx =  o[11], uyy =  o[16];
      const float vxx = -o[10], vyy = -o[13];
      const float l1 = A.lam1[0], l2 = A.lam2[0];
      const float fu = ut + l1 * (u * ux + vv * uy) - l2 * (uxx + uyy);
      const float fv = vt + l1 * (u * vx + vv * vy) - l2 * (vxx + vyy);
      A.out[p]            = u;
      A.out[NPTS + p]     = vv;
      A.out[2 * NPTS + p] = fu;
      A.out[3 * NPTS + p] = fv;
    }
  }
}

extern "C" void kernel_launch(void* const* d_in, const int* in_sizes, int n_in,
                              void* d_out, int out_size, void* d_ws, size_t ws_size,
                              hipStream_t stream) {
  PinnArgs A;
  A.x = (const float*)d_in[0];
  A.y = (const float*)d_in[1];
  A.t = (const float*)d_in[2];
  for (int i = 0; i < 9; ++i) {
    A.W[i] = (const float*)d_in[3 + 2 * i];
    A.b[i] = (const float*)d_in[4 + 2 * i];
  }
  A.lam1 = (const float*)d_in[21];
  A.lam2 = (const float*)d_in[22];
  A.out  = (float*)d_out;
  A.wt   = (const _Float16*)d_ws;

  const size_t need = (size_t)7 * 2 * 16384 * sizeof(_Float16);  // 458752 B
  if (ws_size >= need) {
    PrepArgs P;
    for (int L = 1; L <= 7; ++L) P.W[L - 1] = (const float*)d_in[3 + 2 * L];
    P.out = (_Float16*)d_ws;
    hipLaunchKernelGGL(prep_w16, dim3((7 * 16384) / 256), dim3(256), 0, stream, P);
    hipLaunchKernelGGL(pinn_mfma, dim3(NPTS / PPB), dim3(256), 0, stream, A);
  } else {
    hipLaunchKernelGGL(pinn_fp32, dim3(NPTS / 4), dim3(256), 0, stream, A);
  }
}